// Round 11
// baseline (114.733 us; speedup 1.0000x reference)
//
#include <hip/hip_runtime.h>
#include <hip/hip_bf16.h>

// out = v + 0.5*mask*(softmax_m(mem@v^T - 0.5*||mem||^2)^T @ mem - v)
//  k_prep2 : FUSED: memg f32 -> memA bf16 [m][d] + memTt [m>>4][d][m&15] + msq; v -> vbf
//  k_ref   : per-b reference max over split-0's 512 memories -> pref[16][b]
//            (fixed-reference softmax: exp(S - ref) bounded by e^~60, no online max)
//  k_stage1: 512 WGs (256 thr, lb(256,2)) = 128 m-splits x 4 b-tiles, 16 chunks.
//            32x32x16 MFMA, dbuf global_load_lds staging of memA (QK) + memTt (PV,
//            swizzled), NO max tracking / NO rescale: P = exp(S - ref), rs += tree-sum.
//            One barrier per chunk. Register epilogue to part_o[s][dblk][b][4] + part_l.
//  k_out   : sum partials + divide by sum of part_l + v/mask epilogue

#define NSPLIT 128
#define NCHUNK 16
#define NREF 16

typedef __attribute__((ext_vector_type(4))) float f32x4;
typedef __attribute__((ext_vector_type(16))) float f32x16;
typedef __attribute__((ext_vector_type(8))) short s16x8;
typedef __attribute__((ext_vector_type(2))) unsigned int u32x2;
typedef __attribute__((ext_vector_type(4))) unsigned int u32x4;

__device__ __forceinline__ unsigned short bf16rn(float f) {
  unsigned x = __builtin_bit_cast(unsigned, f);
  x += 0x7fffu + ((x >> 16) & 1u);
  return (unsigned short)(x >> 16);
}
__device__ __forceinline__ unsigned pk2(float a, float b) {
  return (unsigned)bf16rn(a) | ((unsigned)bf16rn(b) << 16);
}
__device__ __forceinline__ float bf2f(unsigned short u) {
  return __builtin_bit_cast(float, ((unsigned)u) << 16);
}

// ---------------- kernel 0: fused prep ----------------
// WG < 2048: slab of 32 m. Writes memA row-major + msq + memTt (via LDS transpose).
// WG >= 2048: v -> vbf.
__global__ __launch_bounds__(256) void k_prep2(const float* __restrict__ memg,
                                               const float* __restrict__ v,
                                               unsigned short* __restrict__ memA,
                                               unsigned short* __restrict__ memTt,
                                               unsigned short* __restrict__ vbf,
                                               float* __restrict__ msq) {
  __shared__ __align__(16) char sl[32 * 528];
  const int wg = (int)blockIdx.x, t = (int)threadIdx.x;
  if (wg < 2048) {
    const int mm = t >> 3, dp = t & 7;  // row mm (0..31), d-block dp (32 d each)
    const size_t m = (size_t)wg * 32 + mm;
    f32x4 f[8];
#pragma unroll
    for (int i = 0; i < 8; ++i)
      f[i] = *reinterpret_cast<const f32x4*>(memg + m * 256 + dp * 32 + i * 4);
    float sq = 0.f;
#pragma unroll
    for (int i = 0; i < 8; ++i)
      sq += f[i][0]*f[i][0] + f[i][1]*f[i][1] + f[i][2]*f[i][2] + f[i][3]*f[i][3];
    sq += __shfl_xor(sq, 1);
    sq += __shfl_xor(sq, 2);
    sq += __shfl_xor(sq, 4);
    if (dp == 0) msq[m] = sq;
    unsigned pk[16];
#pragma unroll
    for (int i = 0; i < 8; ++i) {
      pk[2*i]   = pk2(f[i][0], f[i][1]);
      pk[2*i+1] = pk2(f[i][2], f[i][3]);
    }
    // memA (contiguous 64B per thread)
#pragma unroll
    for (int j = 0; j < 4; ++j) {
      u32x4 o;
      o[0]=pk[4*j]; o[1]=pk[4*j+1]; o[2]=pk[4*j+2]; o[3]=pk[4*j+3];
      *reinterpret_cast<u32x4*>(memA + m * 256 + dp * 32 + j * 8) = o;
    }
    // LDS staging for transpose (row mm padded to 528B)
#pragma unroll
    for (int j = 0; j < 4; ++j) {
      u32x4 o;
      o[0]=pk[4*j]; o[1]=pk[4*j+1]; o[2]=pk[4*j+2]; o[3]=pk[4*j+3];
      *reinterpret_cast<u32x4*>(sl + mm * 528 + dp * 64 + j * 16) = o;
    }
    __syncthreads();
    // memTt output (verified r8 form): block h holds m in [wg*32+h*16, +16)
#pragma unroll
    for (int h = 0; h < 2; ++h) {
      const int d = t;  // 0..255
      unsigned wbuf[8];
#pragma unroll
      for (int i = 0; i < 8; ++i) {
        unsigned lo = *reinterpret_cast<const unsigned short*>(sl + (h * 16 + 2 * i) * 528 + d * 2);
        unsigned hv = *reinterpret_cast<const unsigned short*>(sl + (h * 16 + 2 * i + 1) * 528 + d * 2);
        wbuf[i] = lo | (hv << 16);
      }
      char* dst = (char*)memTt + ((size_t)wg * 2 + h) * 8192 + (size_t)d * 32;
      u32x4 o0, o1;
      o0[0]=wbuf[0]; o0[1]=wbuf[1]; o0[2]=wbuf[2]; o0[3]=wbuf[3];
      o1[0]=wbuf[4]; o1[1]=wbuf[5]; o1[2]=wbuf[6]; o1[3]=wbuf[7];
      *reinterpret_cast<u32x4*>(dst) = o0;
      *reinterpret_cast<u32x4*>(dst + 16) = o1;
    }
  } else {
    const int idx = wg - 2048;  // 0..15
    const size_t e0 = (size_t)idx * 8192 + (size_t)t * 32;
#pragma unroll
    for (int i = 0; i < 8; i += 2) {
      f32x4 f0 = *reinterpret_cast<const f32x4*>(v + e0 + i * 4);
      f32x4 f1 = *reinterpret_cast<const f32x4*>(v + e0 + i * 4 + 4);
      u32x4 o;
      o[0]=pk2(f0[0],f0[1]); o[1]=pk2(f0[2],f0[3]);
      o[2]=pk2(f1[0],f1[1]); o[3]=pk2(f1[2],f1[3]);
      *reinterpret_cast<u32x4*>((char*)vbf + e0 * 2 + i * 8) = o;
    }
  }
}

// ---------------- kernel 0c: reference max over split 0 ----------------
// 64 WGs = 16 m-groups (32 m each, m in [0,512)) x 4 b-tiles. QK only, direct
// global A-fragment reads (L2/L3 resident). pref[mg][b] = max_m logit(m,b).
__global__ __launch_bounds__(256) void k_ref(const unsigned short* __restrict__ memA,
                                             const unsigned short* __restrict__ vbf,
                                             const float* __restrict__ msq,
                                             float* __restrict__ pref) {
  const int tid = (int)threadIdx.x;
  const int w = tid >> 6;
  const int lane = tid & 63;
  const int hi = lane >> 5;
  const int c5 = lane & 31;
  const int mg = (int)blockIdx.x >> 2;
  const int btile = (int)blockIdx.x & 3;
  const int b = btile * 128 + w * 32 + c5;
  const int mc = mg * 32;

  s16x8 vr[16];
#pragma unroll
  for (int k = 0; k < 16; ++k)
    vr[k] = *reinterpret_cast<const s16x8*>(vbf + (size_t)b * 256 + k * 16 + hi * 8);

  f32x16 Sa, Sb = (f32x16)0.0f;
#pragma unroll
  for (int q = 0; q < 4; ++q) {
    f32x4 qq = *reinterpret_cast<const f32x4*>(msq + mc + 8 * q + 4 * hi);
#pragma unroll
    for (int r = 0; r < 4; ++r) Sa[4 * q + r] = -0.5f * qq[r];
  }
  const char* ab = (const char*)memA + ((size_t)(mc + c5)) * 512 + hi * 16;
#pragma unroll
  for (int k = 0; k < 16; k += 2) {
    s16x8 a0 = *reinterpret_cast<const s16x8*>(ab + k * 32);
    s16x8 a1 = *reinterpret_cast<const s16x8*>(ab + k * 32 + 32);
    Sa = __builtin_amdgcn_mfma_f32_32x32x16_bf16(a0, vr[k], Sa, 0, 0, 0);
    Sb = __builtin_amdgcn_mfma_f32_32x32x16_bf16(a1, vr[k + 1], Sb, 0, 0, 0);
  }
  f32x16 S = Sa + Sb;
  float m0 = fmaxf(fmaxf(fmaxf(S[0], S[1]), fmaxf(S[2], S[3])),
                   fmaxf(fmaxf(S[4], S[5]), fmaxf(S[6], S[7])));
  float m1 = fmaxf(fmaxf(fmaxf(S[8], S[9]), fmaxf(S[10], S[11])),
                   fmaxf(fmaxf(S[12], S[13]), fmaxf(S[14], S[15])));
  float mx = fmaxf(m0, m1);
  mx = fmaxf(mx, __shfl_xor(mx, 32));
  if (hi == 0) pref[(size_t)mg * 512 + b] = mx;
}

// ---------------- kernel 1: split-M flash (fixed-reference softmax) ----------------
__global__ __launch_bounds__(256, 2) void k_stage1(
    const unsigned short* __restrict__ memA, const unsigned short* __restrict__ memTt,
    const unsigned short* __restrict__ vbf, const float* __restrict__ msq,
    const float* __restrict__ pref, unsigned short* __restrict__ part_o,
    float* __restrict__ part_l) {
  __shared__ __align__(16) char lds[65536];  // Ab0 16K | Ab1 16K | Tt0 16K | Tt1 16K
  char* const Ab0 = lds;
  char* const Ab1 = lds + 16384;
  char* const Tt0 = lds + 32768;
  char* const Tt1 = lds + 49152;

  const int tid = (int)threadIdx.x;
  const int w = tid >> 6;
  const int lane = tid & 63;
  const int hi = lane >> 5;
  const int c5 = lane & 31;

  const int bid = (int)blockIdx.x;
  const int swz = (bid & 7) * 64 + (bid >> 3);
  const int s = swz >> 2;     // m-split 0..127
  const int btile = swz & 3;  // 0..3
  const int bw = btile * 128 + w * 32;
  const int b = bw + c5;

  const char* Ac = (const char*)memA;
  const size_t qsrc = (size_t)s * 262144 + (size_t)(tid >> 5) * 512 +
                      (size_t)(((tid & 31) ^ (tid >> 5)) * 16);
  const char* Tc = (const char*)memTt;
  const size_t tsrc = (size_t)s * 262144 + (size_t)w * 1024 +
                      (size_t)(((unsigned)lane * 16u) ^ ((unsigned)lane & 16u));

#define STAGE_A(bufp, t_)                                                        \
  do {                                                                           \
    _Pragma("unroll") for (int i_ = 0; i_ < 4; ++i_) {                           \
      __builtin_amdgcn_global_load_lds(                                          \
          (const __attribute__((address_space(1))) void*)(Ac + qsrc +            \
              (size_t)(t_) * 16384 + (size_t)i_ * 4096),                         \
          (__attribute__((address_space(3))) void*)((bufp) + w * 1024 + i_ * 4096), \
          16, 0, 0);                                                             \
    }                                                                            \
  } while (0)
#define STAGE_T(bufp, t_)                                                        \
  do {                                                                           \
    _Pragma("unroll") for (int i_ = 0; i_ < 4; ++i_) {                           \
      __builtin_amdgcn_global_load_lds(                                          \
          (const __attribute__((address_space(1))) void*)(Tc + tsrc +            \
              (size_t)(t_) * 16384 + (size_t)i_ * 4096),                         \
          (__attribute__((address_space(3))) void*)((bufp) + w * 1024 + i_ * 4096), \
          16, 0, 0);                                                             \
    }                                                                            \
  } while (0)

  f32x16 acc[8];
#pragma unroll
  for (int n = 0; n < 8; ++n) acc[n] = (f32x16)0.0f;
  float rs = 0.f;

  s16x8 vr[16];
  STAGE_A(Ab0, 0);
  STAGE_T(Tt0, 0);
#pragma unroll
  for (int k = 0; k < 16; ++k)
    vr[k] = *reinterpret_cast<const s16x8*>(vbf + (size_t)b * 256 + k * 16 + hi * 8);

  // fixed per-b reference (any bounded value is correct; cancels in k_out)
  float ref = pref[b];
#pragma unroll
  for (int g = 1; g < NREF; ++g) ref = fmaxf(ref, pref[(size_t)g * 512 + b]);
  const float nref = -ref;

  asm volatile("s_waitcnt vmcnt(0)" ::: "memory");
  __builtin_amdgcn_s_barrier();
  asm volatile("" ::: "memory");

  for (int t = 0; t < NCHUNK; ++t) {
    char* Abc = (t & 1) ? Ab1 : Ab0;
    char* Abn = (t & 1) ? Ab0 : Ab1;
    char* Ttc = (t & 1) ? Tt1 : Tt0;
    char* Ttn = (t & 1) ? Tt0 : Tt1;
    if (t < NCHUNK - 1) {
      STAGE_A(Abn, t + 1);
      STAGE_T(Ttn, t + 1);
    }

    // ---- QK^T with bias+ref folded into Sa init ----
    const int mc = s * 512 + t * 32;
    f32x16 Sa, Sb = (f32x16)0.0f;
#pragma unroll
    for (int q = 0; q < 4; ++q) {
      f32x4 qq = *reinterpret_cast<const f32x4*>(msq + mc + 8 * q + 4 * hi);
#pragma unroll
      for (int r = 0; r < 4; ++r) Sa[4 * q + r] = fmaf(qq[r], -0.5f, nref);
    }
    const char* qb = Abc + c5 * 512;
#pragma unroll
    for (int k = 0; k < 16; k += 2) {
      s16x8 a0 = *reinterpret_cast<const s16x8*>(qb + ((k * 32 + hi * 16) ^ ((c5 & 7) << 4)));
      s16x8 a1 = *reinterpret_cast<const s16x8*>(qb + (((k + 1) * 32 + hi * 16) ^ ((c5 & 7) << 4)));
      Sa = __builtin_amdgcn_mfma_f32_32x32x16_bf16(a0, vr[k], Sa, 0, 0, 0);
      Sb = __builtin_amdgcn_mfma_f32_32x32x16_bf16(a1, vr[k + 1], Sb, 0, 0, 0);
    }
    f32x16 S = Sa + Sb;

    // ---- fixed-reference softmax: P = exp(S), tree-sum, no max/rescale ----
#pragma unroll
    for (int i = 0; i < 16; ++i) S[i] = __expf(S[i]);
    {
      float t0 = (S[0] + S[1]) + (S[2] + S[3]);
      float t1 = (S[4] + S[5]) + (S[6] + S[7]);
      float t2 = (S[8] + S[9]) + (S[10] + S[11]);
      float t3 = (S[12] + S[13]) + (S[14] + S[15]);
      rs += (t0 + t1) + (t2 + t3);
    }

    // ---- P -> B-fragments (verified lane shuffle) ----
    unsigned pkd[8];
#pragma unroll
    for (int p = 0; p < 8; ++p) pkd[p] = pk2(S[2 * p], S[2 * p + 1]);
    s16x8 pb0, pb1;
#pragma unroll
    for (int kk = 0; kk < 2; ++kk) {
      u32x4 wv;
#pragma unroll
      for (int i = 0; i < 4; ++i) {
        const int src = (i >> 1) * 32 + c5;
        unsigned lo = (unsigned)__shfl((int)pkd[(i & 1) + 4 * kk], src);
        unsigned hv = (unsigned)__shfl((int)pkd[(i & 1) + 4 * kk + 2], src);
        wv[i] = hi ? hv : lo;
      }
      if (kk == 0) pb0 = __builtin_bit_cast(s16x8, wv);
      else         pb1 = __builtin_bit_cast(s16x8, wv);
    }

    // ---- PV: acc[d][b] += memT @ P (A = LDS Tt, swizzled reads) ----
#pragma unroll
    for (int n = 0; n < 8; ++n) {
      const int ro = n * 1024 + c5 * 32 + ((hi * 16) ^ ((c5 & 8) << 1));
      s16x8 bm0 = *reinterpret_cast<const s16x8*>(Ttc + ro);
      s16x8 bm1 = *reinterpret_cast<const s16x8*>(Ttc + ro + 8192);
      acc[n] = __builtin_amdgcn_mfma_f32_32x32x16_bf16(bm0, pb0, acc[n], 0, 0, 0);
      acc[n] = __builtin_amdgcn_mfma_f32_32x32x16_bf16(bm1, pb1, acc[n], 0, 0, 0);
    }

    asm volatile("s_waitcnt vmcnt(0)" ::: "memory");
    __builtin_amdgcn_s_barrier();
    asm volatile("" ::: "memory");
  }

  // ---- denominator partial [s][b] ----
  rs += __shfl_xor(rs, 32);
  if (hi == 0) part_l[(size_t)s * 512 + b] = rs;

  // ---- epilogue: direct coalesced stores, part_o[s][dblk(64)][b(512)][4] ----
#pragma unroll
  for (int n = 0; n < 8; ++n) {
#pragma unroll
    for (int q = 0; q < 4; ++q) {
      u32x2 pw;
      pw[0] = pk2(acc[n][4 * q + 0], acc[n][4 * q + 1]);
      pw[1] = pk2(acc[n][4 * q + 2], acc[n][4 * q + 3]);
      *reinterpret_cast<u32x2*>(part_o + (size_t)s * 131072 +
                                (size_t)(n * 8 + 2 * q + hi) * 2048 + (size_t)b * 4) = pw;
    }
  }
#undef STAGE_A
#undef STAGE_T
}

// ---------------- kernel 2: reduce partials + normalize + epilogue ----------------
__global__ __launch_bounds__(128) void k_out(const unsigned short* __restrict__ part_o,
                                             const float* __restrict__ part_l,
                                             const float* __restrict__ v,
                                             const float* __restrict__ mask,
                                             float* __restrict__ out) {
  const int dblk = (int)blockIdx.x >> 2;                         // 0..63
  const int b = ((int)blockIdx.x & 3) * 128 + (int)threadIdx.x;  // 0..511
  float a0 = 0.f, a1 = 0.f, a2 = 0.f, a3 = 0.f, Z = 0.f;
  const unsigned short* po = part_o + (size_t)dblk * 2048 + (size_t)b * 4;
#pragma unroll 8
  for (int gi = 0; gi < NSPLIT; ++gi) {
    u32x2 pw = *reinterpret_cast<const u32x2*>(po + (size_t)gi * 131072);
    Z += part_l[(size_t)gi * 512 + b];
    a0 += bf2f((unsigned short)pw[0]);
    a1 += bf2f((unsigned short)(pw[0] >> 16));
    a2 += bf2f((unsigned short)pw[1]);
    a3 += bf2f((unsigned short)(pw[1] >> 16));
  }
  const float inv = 1.0f / Z;
  const size_t idx = (size_t)b * 256 + (size_t)dblk * 4;
  f32x4 vv = *reinterpret_cast<const f32x4*>(v + idx);
  f32x4 mk = *reinterpret_cast<const f32x4*>(mask + idx);
  f32x4 o;
  o[0] = vv[0] + 0.5f * (a0 * inv - vv[0]) * mk[0];
  o[1] = vv[1] + 0.5f * (a1 * inv - vv[1]) * mk[1];
  o[2] = vv[2] + 0.5f * (a2 * inv - vv[2]) * mk[2];
  o[3] = vv[3] + 0.5f * (a3 * inv - vv[3]) * mk[3];
  *reinterpret_cast<f32x4*>(out + idx) = o;
}

extern "C" void kernel_launch(void* const* d_in, const int* in_sizes, int n_in,
                              void* d_out, int out_size, void* d_ws, size_t ws_size,
                              hipStream_t stream) {
  const float* v = (const float*)d_in[0];       // [512,256]
  const float* mask = (const float*)d_in[1];    // [512,256]
  const float* memg = (const float*)d_in[2];    // [65536,256]
  float* out = (float*)d_out;

  char* ws = (char*)d_ws;
  const size_t SZ_PO = (size_t)NSPLIT * 64 * 512 * 4 * 2;  // 32 MiB
  const size_t SZ_MA = (size_t)65536 * 256 * 2;            // 32 MiB
  const size_t SZ_MS = (size_t)65536 * 4;                  // 256 KiB
  const size_t SZ_VB = (size_t)512 * 256 * 2;              // 256 KiB
  const size_t SZ_PL = (size_t)NSPLIT * 512 * 4;           // 256 KiB
  const size_t SZ_PR = (size_t)NSPLIT * 512 * 4;           // 256 KiB (pref uses 32K)
  unsigned short* part_o = (unsigned short*)ws;
  unsigned short* memA = (unsigned short*)(ws + SZ_PO);
  float* msq = (float*)(ws + SZ_PO + SZ_MA);
  unsigned short* vbf = (unsigned short*)(ws + SZ_PO + SZ_MA + SZ_MS);
  float* part_l = (float*)(ws + SZ_PO + SZ_MA + SZ_MS + SZ_VB);
  float* pref = (float*)(ws + SZ_PO + SZ_MA + SZ_MS + SZ_VB + SZ_PL);
  unsigned short* memTt = (unsigned short*)(ws + SZ_PO + SZ_MA + SZ_MS + SZ_VB + SZ_PL + SZ_PR);

  k_prep2<<<dim3(2064), dim3(256), 0, stream>>>(memg, v, memA, memTt, vbf, msq);
  k_ref<<<dim3(64), dim3(256), 0, stream>>>(memA, vbf, msq, pref);
  k_stage1<<<dim3(512), dim3(256), 0, stream>>>(memA, memTt, vbf, msq, pref, part_o, part_l);
  k_out<<<dim3(256), dim3(128), 0, stream>>>(part_o, part_l, v, mask, out);
}

// Round 12
// 111.641 us; speedup vs baseline: 1.0277x; 1.0277x over previous
//
#include <hip/hip_runtime.h>
#include <hip/hip_bf16.h>

// out = v + 0.5*mask*(softmax_m(mem@v^T - 0.5*||mem||^2)^T @ mem - v)
//  k_prep2 : FUSED: memg f32 -> memA bf16 [m][d] + memTt [m>>4][d][m&15] + msq; v -> vbf
//  k_ref   : per-b reference max over split-0's 512 memories -> pref[16][b]
//  k_stage1: 512 WGs (256 thr, lb(256,2)) = 128 m-splits x 4 b-tiles, 16 chunks.
//            32x32x16 MFMA, dbuf global_load_lds staging (memA QK + memTt PV swz).
//            Fixed-reference softmax: P = exp(S - 0.5*msq - ref), tree-sum only.
//            msq prefetched to regs BEFORE the QK loop, bias applied AFTER it
//            (keeps loads off the MFMA critical path). s_setprio around MFMA
//            clusters (2 blocks/CU at staggered phases -> arbitration pays).
//  k_out   : sum partials + normalize + v/mask epilogue

#define NSPLIT 128
#define NCHUNK 16
#define NREF 16

typedef __attribute__((ext_vector_type(4))) float f32x4;
typedef __attribute__((ext_vector_type(16))) float f32x16;
typedef __attribute__((ext_vector_type(8))) short s16x8;
typedef __attribute__((ext_vector_type(2))) unsigned int u32x2;
typedef __attribute__((ext_vector_type(4))) unsigned int u32x4;

__device__ __forceinline__ unsigned short bf16rn(float f) {
  unsigned x = __builtin_bit_cast(unsigned, f);
  x += 0x7fffu + ((x >> 16) & 1u);
  return (unsigned short)(x >> 16);
}
__device__ __forceinline__ unsigned pk2(float a, float b) {
  return (unsigned)bf16rn(a) | ((unsigned)bf16rn(b) << 16);
}
__device__ __forceinline__ float bf2f(unsigned short u) {
  return __builtin_bit_cast(float, ((unsigned)u) << 16);
}

// ---------------- kernel 0: fused prep (verified r11) ----------------
__global__ __launch_bounds__(256) void k_prep2(const float* __restrict__ memg,
                                               const float* __restrict__ v,
                                               unsigned short* __restrict__ memA,
                                               unsigned short* __restrict__ memTt,
                                               unsigned short* __restrict__ vbf,
                                               float* __restrict__ msq) {
  __shared__ __align__(16) char sl[32 * 528];
  const int wg = (int)blockIdx.x, t = (int)threadIdx.x;
  if (wg < 2048) {
    const int mm = t >> 3, dp = t & 7;
    const size_t m = (size_t)wg * 32 + mm;
    f32x4 f[8];
#pragma unroll
    for (int i = 0; i < 8; ++i)
      f[i] = *reinterpret_cast<const f32x4*>(memg + m * 256 + dp * 32 + i * 4);
    float sq = 0.f;
#pragma unroll
    for (int i = 0; i < 8; ++i)
      sq += f[i][0]*f[i][0] + f[i][1]*f[i][1] + f[i][2]*f[i][2] + f[i][3]*f[i][3];
    sq += __shfl_xor(sq, 1);
    sq += __shfl_xor(sq, 2);
    sq += __shfl_xor(sq, 4);
    if (dp == 0) msq[m] = sq;
    unsigned pk[16];
#pragma unroll
    for (int i = 0; i < 8; ++i) {
      pk[2*i]   = pk2(f[i][0], f[i][1]);
      pk[2*i+1] = pk2(f[i][2], f[i][3]);
    }
#pragma unroll
    for (int j = 0; j < 4; ++j) {
      u32x4 o;
      o[0]=pk[4*j]; o[1]=pk[4*j+1]; o[2]=pk[4*j+2]; o[3]=pk[4*j+3];
      *reinterpret_cast<u32x4*>(memA + m * 256 + dp * 32 + j * 8) = o;
    }
#pragma unroll
    for (int j = 0; j < 4; ++j) {
      u32x4 o;
      o[0]=pk[4*j]; o[1]=pk[4*j+1]; o[2]=pk[4*j+2]; o[3]=pk[4*j+3];
      *reinterpret_cast<u32x4*>(sl + mm * 528 + dp * 64 + j * 16) = o;
    }
    __syncthreads();
#pragma unroll
    for (int h = 0; h < 2; ++h) {
      const int d = t;
      unsigned wbuf[8];
#pragma unroll
      for (int i = 0; i < 8; ++i) {
        unsigned lo = *reinterpret_cast<const unsigned short*>(sl + (h * 16 + 2 * i) * 528 + d * 2);
        unsigned hv = *reinterpret_cast<const unsigned short*>(sl + (h * 16 + 2 * i + 1) * 528 + d * 2);
        wbuf[i] = lo | (hv << 16);
      }
      char* dst = (char*)memTt + ((size_t)wg * 2 + h) * 8192 + (size_t)d * 32;
      u32x4 o0, o1;
      o0[0]=wbuf[0]; o0[1]=wbuf[1]; o0[2]=wbuf[2]; o0[3]=wbuf[3];
      o1[0]=wbuf[4]; o1[1]=wbuf[5]; o1[2]=wbuf[6]; o1[3]=wbuf[7];
      *reinterpret_cast<u32x4*>(dst) = o0;
      *reinterpret_cast<u32x4*>(dst + 16) = o1;
    }
  } else {
    const int idx = wg - 2048;
    const size_t e0 = (size_t)idx * 8192 + (size_t)t * 32;
#pragma unroll
    for (int i = 0; i < 8; i += 2) {
      f32x4 f0 = *reinterpret_cast<const f32x4*>(v + e0 + i * 4);
      f32x4 f1 = *reinterpret_cast<const f32x4*>(v + e0 + i * 4 + 4);
      u32x4 o;
      o[0]=pk2(f0[0],f0[1]); o[1]=pk2(f0[2],f0[3]);
      o[2]=pk2(f1[0],f1[1]); o[3]=pk2(f1[2],f1[3]);
      *reinterpret_cast<u32x4*>((char*)vbf + e0 * 2 + i * 8) = o;
    }
  }
}

// ---------------- kernel 0c: reference max over split 0 (verified r11) ----------------
__global__ __launch_bounds__(256) void k_ref(const unsigned short* __restrict__ memA,
                                             const unsigned short* __restrict__ vbf,
                                             const float* __restrict__ msq,
                                             float* __restrict__ pref) {
  const int tid = (int)threadIdx.x;
  const int w = tid >> 6;
  const int lane = tid & 63;
  const int hi = lane >> 5;
  const int c5 = lane & 31;
  const int mg = (int)blockIdx.x >> 2;
  const int btile = (int)blockIdx.x & 3;
  const int b = btile * 128 + w * 32 + c5;
  const int mc = mg * 32;

  s16x8 vr[16];
#pragma unroll
  for (int k = 0; k < 16; ++k)
    vr[k] = *reinterpret_cast<const s16x8*>(vbf + (size_t)b * 256 + k * 16 + hi * 8);

  f32x16 Sa, Sb = (f32x16)0.0f;
#pragma unroll
  for (int q = 0; q < 4; ++q) {
    f32x4 qq = *reinterpret_cast<const f32x4*>(msq + mc + 8 * q + 4 * hi);
#pragma unroll
    for (int r = 0; r < 4; ++r) Sa[4 * q + r] = -0.5f * qq[r];
  }
  const char* ab = (const char*)memA + ((size_t)(mc + c5)) * 512 + hi * 16;
#pragma unroll
  for (int k = 0; k < 16; k += 2) {
    s16x8 a0 = *reinterpret_cast<const s16x8*>(ab + k * 32);
    s16x8 a1 = *reinterpret_cast<const s16x8*>(ab + k * 32 + 32);
    Sa = __builtin_amdgcn_mfma_f32_32x32x16_bf16(a0, vr[k], Sa, 0, 0, 0);
    Sb = __builtin_amdgcn_mfma_f32_32x32x16_bf16(a1, vr[k + 1], Sb, 0, 0, 0);
  }
  f32x16 S = Sa + Sb;
  float m0 = fmaxf(fmaxf(fmaxf(S[0], S[1]), fmaxf(S[2], S[3])),
                   fmaxf(fmaxf(S[4], S[5]), fmaxf(S[6], S[7])));
  float m1 = fmaxf(fmaxf(fmaxf(S[8], S[9]), fmaxf(S[10], S[11])),
                   fmaxf(fmaxf(S[12], S[13]), fmaxf(S[14], S[15])));
  float mx = fmaxf(m0, m1);
  mx = fmaxf(mx, __shfl_xor(mx, 32));
  if (hi == 0) pref[(size_t)mg * 512 + b] = mx;
}

// ---------------- kernel 1: split-M flash (fixed-ref softmax, overlap-safe) ----------------
__global__ __launch_bounds__(256, 2) void k_stage1(
    const unsigned short* __restrict__ memA, const unsigned short* __restrict__ memTt,
    const unsigned short* __restrict__ vbf, const float* __restrict__ msq,
    const float* __restrict__ pref, unsigned short* __restrict__ part_o,
    float* __restrict__ part_l) {
  __shared__ __align__(16) char lds[65536];  // Ab0 16K | Ab1 16K | Tt0 16K | Tt1 16K
  char* const Ab0 = lds;
  char* const Ab1 = lds + 16384;
  char* const Tt0 = lds + 32768;
  char* const Tt1 = lds + 49152;

  const int tid = (int)threadIdx.x;
  const int w = tid >> 6;
  const int lane = tid & 63;
  const int hi = lane >> 5;
  const int c5 = lane & 31;

  const int bid = (int)blockIdx.x;
  const int swz = (bid & 7) * 64 + (bid >> 3);
  const int s = swz >> 2;     // m-split 0..127
  const int btile = swz & 3;  // 0..3
  const int bw = btile * 128 + w * 32;
  const int b = bw + c5;

  const char* Ac = (const char*)memA;
  const size_t qsrc = (size_t)s * 262144 + (size_t)(tid >> 5) * 512 +
                      (size_t)(((tid & 31) ^ (tid >> 5)) * 16);
  const char* Tc = (const char*)memTt;
  const size_t tsrc = (size_t)s * 262144 + (size_t)w * 1024 +
                      (size_t)(((unsigned)lane * 16u) ^ ((unsigned)lane & 16u));

#define STAGE_A(bufp, t_)                                                        \
  do {                                                                           \
    _Pragma("unroll") for (int i_ = 0; i_ < 4; ++i_) {                           \
      __builtin_amdgcn_global_load_lds(                                          \
          (const __attribute__((address_space(1))) void*)(Ac + qsrc +            \
              (size_t)(t_) * 16384 + (size_t)i_ * 4096),                         \
          (__attribute__((address_space(3))) void*)((bufp) + w * 1024 + i_ * 4096), \
          16, 0, 0);                                                             \
    }                                                                            \
  } while (0)
#define STAGE_T(bufp, t_)                                                        \
  do {                                                                           \
    _Pragma("unroll") for (int i_ = 0; i_ < 4; ++i_) {                           \
      __builtin_amdgcn_global_load_lds(                                          \
          (const __attribute__((address_space(1))) void*)(Tc + tsrc +            \
              (size_t)(t_) * 16384 + (size_t)i_ * 4096),                         \
          (__attribute__((address_space(3))) void*)((bufp) + w * 1024 + i_ * 4096), \
          16, 0, 0);                                                             \
    }                                                                            \
  } while (0)

  f32x16 acc[8];
#pragma unroll
  for (int n = 0; n < 8; ++n) acc[n] = (f32x16)0.0f;
  float rs = 0.f;

  s16x8 vr[16];
  STAGE_A(Ab0, 0);
  STAGE_T(Tt0, 0);
#pragma unroll
  for (int k = 0; k < 16; ++k)
    vr[k] = *reinterpret_cast<const s16x8*>(vbf + (size_t)b * 256 + k * 16 + hi * 8);

  // fixed per-b reference (bounded; cancels in k_out)
  float ref = pref[b];
#pragma unroll
  for (int g = 1; g < NREF; ++g) ref = fmaxf(ref, pref[(size_t)g * 512 + b]);
  const float nref = -ref;

  asm volatile("s_waitcnt vmcnt(0)" ::: "memory");
  __builtin_amdgcn_s_barrier();
  asm volatile("" ::: "memory");

  for (int t = 0; t < NCHUNK; ++t) {
    char* Abc = (t & 1) ? Ab1 : Ab0;
    char* Abn = (t & 1) ? Ab0 : Ab1;
    char* Ttc = (t & 1) ? Tt1 : Tt0;
    char* Ttn = (t & 1) ? Tt0 : Tt1;
    if (t < NCHUNK - 1) {
      STAGE_A(Abn, t + 1);
      STAGE_T(Ttn, t + 1);
    }

    // ---- msq prefetch (issue loads now; consumed after the MFMA loop) ----
    const int mc = s * 512 + t * 32;
    f32x4 qq[4];
#pragma unroll
    for (int q = 0; q < 4; ++q)
      qq[q] = *reinterpret_cast<const f32x4*>(msq + mc + 8 * q + 4 * hi);

    // ---- QK^T: S[32m][32b], two accumulation chains ----
    const char* qb = Abc + c5 * 512;
    f32x16 Sa = (f32x16)0.0f, Sb = (f32x16)0.0f;
    __builtin_amdgcn_s_setprio(1);
#pragma unroll
    for (int k = 0; k < 16; k += 2) {
      s16x8 a0 = *reinterpret_cast<const s16x8*>(qb + ((k * 32 + hi * 16) ^ ((c5 & 7) << 4)));
      s16x8 a1 = *reinterpret_cast<const s16x8*>(qb + (((k + 1) * 32 + hi * 16) ^ ((c5 & 7) << 4)));
      Sa = __builtin_amdgcn_mfma_f32_32x32x16_bf16(a0, vr[k], Sa, 0, 0, 0);
      Sb = __builtin_amdgcn_mfma_f32_32x32x16_bf16(a1, vr[k + 1], Sb, 0, 0, 0);
    }
    __builtin_amdgcn_s_setprio(0);
    f32x16 S = Sa + Sb;

    // ---- fixed-reference softmax: P = exp(S - 0.5*msq - ref), tree-sum ----
#pragma unroll
    for (int q = 0; q < 4; ++q)
#pragma unroll
      for (int r = 0; r < 4; ++r)
        S[4 * q + r] = __expf(fmaf(qq[q][r], -0.5f, nref) + S[4 * q + r]);
    {
      float t0 = (S[0] + S[1]) + (S[2] + S[3]);
      float t1 = (S[4] + S[5]) + (S[6] + S[7]);
      float t2 = (S[8] + S[9]) + (S[10] + S[11]);
      float t3 = (S[12] + S[13]) + (S[14] + S[15]);
      rs += (t0 + t1) + (t2 + t3);
    }

    // ---- P -> B-fragments (verified lane shuffle) ----
    unsigned pkd[8];
#pragma unroll
    for (int p = 0; p < 8; ++p) pkd[p] = pk2(S[2 * p], S[2 * p + 1]);
    s16x8 pb0, pb1;
#pragma unroll
    for (int kk = 0; kk < 2; ++kk) {
      u32x4 wv;
#pragma unroll
      for (int i = 0; i < 4; ++i) {
        const int src = (i >> 1) * 32 + c5;
        unsigned lo = (unsigned)__shfl((int)pkd[(i & 1) + 4 * kk], src);
        unsigned hv = (unsigned)__shfl((int)pkd[(i & 1) + 4 * kk + 2], src);
        wv[i] = hi ? hv : lo;
      }
      if (kk == 0) pb0 = __builtin_bit_cast(s16x8, wv);
      else         pb1 = __builtin_bit_cast(s16x8, wv);
    }

    // ---- PV: acc[d][b] += memT @ P (A = LDS Tt, swizzled reads) ----
    __builtin_amdgcn_s_setprio(1);
#pragma unroll
    for (int n = 0; n < 8; ++n) {
      const int ro = n * 1024 + c5 * 32 + ((hi * 16) ^ ((c5 & 8) << 1));
      s16x8 bm0 = *reinterpret_cast<const s16x8*>(Ttc + ro);
      s16x8 bm1 = *reinterpret_cast<const s16x8*>(Ttc + ro + 8192);
      acc[n] = __builtin_amdgcn_mfma_f32_32x32x16_bf16(bm0, pb0, acc[n], 0, 0, 0);
      acc[n] = __builtin_amdgcn_mfma_f32_32x32x16_bf16(bm1, pb1, acc[n], 0, 0, 0);
    }
    __builtin_amdgcn_s_setprio(0);

    asm volatile("s_waitcnt vmcnt(0)" ::: "memory");
    __builtin_amdgcn_s_barrier();
    asm volatile("" ::: "memory");
  }

  // ---- denominator partial [s][b] ----
  rs += __shfl_xor(rs, 32);
  if (hi == 0) part_l[(size_t)s * 512 + b] = rs;

  // ---- epilogue: direct coalesced stores, part_o[s][dblk(64)][b(512)][4] ----
#pragma unroll
  for (int n = 0; n < 8; ++n) {
#pragma unroll
    for (int q = 0; q < 4; ++q) {
      u32x2 pw;
      pw[0] = pk2(acc[n][4 * q + 0], acc[n][4 * q + 1]);
      pw[1] = pk2(acc[n][4 * q + 2], acc[n][4 * q + 3]);
      *reinterpret_cast<u32x2*>(part_o + (size_t)s * 131072 +
                                (size_t)(n * 8 + 2 * q + hi) * 2048 + (size_t)b * 4) = pw;
    }
  }
#undef STAGE_A
#undef STAGE_T
}

// ---------------- kernel 2: reduce partials + normalize + epilogue (verified r11) ----------------
__global__ __launch_bounds__(128) void k_out(const unsigned short* __restrict__ part_o,
                                             const float* __restrict__ part_l,
                                             const float* __restrict__ v,
                                             const float* __restrict__ mask,
                                             float* __restrict__ out) {
  const int dblk = (int)blockIdx.x >> 2;                         // 0..63
  const int b = ((int)blockIdx.x & 3) * 128 + (int)threadIdx.x;  // 0..511
  float a0 = 0.f, a1 = 0.f, a2 = 0.f, a3 = 0.f, Z = 0.f;
  const unsigned short* po = part_o + (size_t)dblk * 2048 + (size_t)b * 4;
#pragma unroll 8
  for (int gi = 0; gi < NSPLIT; ++gi) {
    u32x2 pw = *reinterpret_cast<const u32x2*>(po + (size_t)gi * 131072);
    Z += part_l[(size_t)gi * 512 + b];
    a0 += bf2f((unsigned short)pw[0]);
    a1 += bf2f((unsigned short)(pw[0] >> 16));
    a2 += bf2f((unsigned short)pw[1]);
    a3 += bf2f((unsigned short)(pw[1] >> 16));
  }
  const float inv = 1.0f / Z;
  const size_t idx = (size_t)b * 256 + (size_t)dblk * 4;
  f32x4 vv = *reinterpret_cast<const f32x4*>(v + idx);
  f32x4 mk = *reinterpret_cast<const f32x4*>(mask + idx);
  f32x4 o;
  o[0] = vv[0] + 0.5f * (a0 * inv - vv[0]) * mk[0];
  o[1] = vv[1] + 0.5f * (a1 * inv - vv[1]) * mk[1];
  o[2] = vv[2] + 0.5f * (a2 * inv - vv[2]) * mk[2];
  o[3] = vv[3] + 0.5f * (a3 * inv - vv[3]) * mk[3];
  *reinterpret_cast<f32x4*>(out + idx) = o;
}

extern "C" void kernel_launch(void* const* d_in, const int* in_sizes, int n_in,
                              void* d_out, int out_size, void* d_ws, size_t ws_size,
                              hipStream_t stream) {
  const float* v = (const float*)d_in[0];       // [512,256]
  const float* mask = (const float*)d_in[1];    // [512,256]
  const float* memg = (const float*)d_in[2];    // [65536,256]
  float* out = (float*)d_out;

  char* ws = (char*)d_ws;
  const size_t SZ_PO = (size_t)NSPLIT * 64 * 512 * 4 * 2;  // 32 MiB
  const size_t SZ_MA = (size_t)65536 * 256 * 2;            // 32 MiB
  const size_t SZ_MS = (size_t)65536 * 4;                  // 256 KiB
  const size_t SZ_VB = (size_t)512 * 256 * 2;              // 256 KiB
  const size_t SZ_PL = (size_t)NSPLIT * 512 * 4;           // 256 KiB
  const size_t SZ_PR = (size_t)NSPLIT * 512 * 4;           // 256 KiB (pref uses 32K)
  unsigned short* part_o = (unsigned short*)ws;
  unsigned short* memA = (unsigned short*)(ws + SZ_PO);
  float* msq = (float*)(ws + SZ_PO + SZ_MA);
  unsigned short* vbf = (unsigned short*)(ws + SZ_PO + SZ_MA + SZ_MS);
  float* part_l = (float*)(ws + SZ_PO + SZ_MA + SZ_MS + SZ_VB);
  float* pref = (float*)(ws + SZ_PO + SZ_MA + SZ_MS + SZ_VB + SZ_PL);
  unsigned short* memTt = (unsigned short*)(ws + SZ_PO + SZ_MA + SZ_MS + SZ_VB + SZ_PL + SZ_PR);

  k_prep2<<<dim3(2064), dim3(256), 0, stream>>>(memg, v, memA, memTt, vbf, msq);
  k_ref<<<dim3(64), dim3(256), 0, stream>>>(memA, vbf, msq, pref);
  k_stage1<<<dim3(512), dim3(256), 0, stream>>>(memA, memTt, vbf, msq, pref, part_o, part_l);
  k_out<<<dim3(256), dim3(128), 0, stream>>>(part_o, part_l, v, mask, out);
}